// Round 2
// baseline (276.565 us; speedup 1.0000x reference)
//
#include <hip/hip_runtime.h>
#include <stdint.h>

// ============================================================================
// ExpertMLP: out = relu(x @ W_fc^T)^2 @ W_proj^T
// Harness dtypes per reference: fp32 inputs, fp32 output.
// Strategy: fp32->bf16 prepass into d_ws, then two m97-style bf16 MFMA GEMMs
// (128x128 tile, BK=32, 16x16x32 bf16 MFMA, global_load_lds width=16).
// relu^2 fused into GEMM1 epilogue (bf16 h in ws); GEMM2 stores fp32.
// ws layout: h[64Mi] | x_bf[16Mi] | wfc_bf[8Mi] | wproj_bf[8Mi] = 96 MiB.
// ============================================================================

#define BM 128
#define BN 128
#define BK 32

typedef __attribute__((ext_vector_type(8))) short bf16x8;   // 8 bf16 = 4 VGPRs
typedef __attribute__((ext_vector_type(4))) float f32x4;    // MFMA C/D

typedef const __attribute__((address_space(1))) unsigned int* gas_u32p;
typedef __attribute__((address_space(3))) unsigned int* las_u32p;

__device__ __forceinline__ void load16_to_lds(const void* gptr, void* lptr) {
    // async global->LDS, 16 B per lane; LDS dst = wave-uniform base + lane*16
    __builtin_amdgcn_global_load_lds((gas_u32p)gptr, (las_u32p)lptr, 16, 0, 0);
}

__device__ __forceinline__ unsigned short f2bf(float f) {
    // RNE fp32 -> bf16 (no NaN inputs in this problem)
    unsigned int u = __float_as_uint(f);
    u += 0x7FFFu + ((u >> 16) & 1u);
    return (unsigned short)(u >> 16);
}

// --------------------------------------------------------------------------
// fp32 -> bf16 conversion, float4 in / ushort4 out, grid-stride
// --------------------------------------------------------------------------
__global__ void cvt_f32_bf16(const float4* __restrict__ src,
                             ushort4* __restrict__ dst, int n4)
{
    int i = blockIdx.x * blockDim.x + threadIdx.x;
    int stride = gridDim.x * blockDim.x;
    for (; i < n4; i += stride) {
        float4 v = src[i];
        ushort4 o;
        o.x = f2bf(v.x); o.y = f2bf(v.y); o.z = f2bf(v.z); o.w = f2bf(v.w);
        dst[i] = o;
    }
}

// --------------------------------------------------------------------------
// C[M,N] = A[M,K] . B[N,K]^T  (A,B bf16-as-ushort; fp32 accum)
// RELU2: v = relu(v)^2 in epilogue.  OUT_BF16: store bf16, else fp32.
// Requires M%128==0, N%128==0, K%32==0.
// --------------------------------------------------------------------------
template<bool RELU2, bool OUT_BF16>
__global__ __launch_bounds__(256, 3)
void gemm_bt(const unsigned short* __restrict__ A,
             const unsigned short* __restrict__ B,
             void* __restrict__ Cv, int M, int N, int K)
{
    __shared__ unsigned short sA[BM * BK];   // 8 KiB, row-major [128][32]
    __shared__ unsigned short sB[BN * BK];   // 8 KiB

    const int tid  = threadIdx.x;        // 0..255 (4 waves)
    const int lane = tid & 63;
    const int wave = tid >> 6;
    const int wm   = (wave >> 1) * 64;   // wave tile origin in M
    const int wn   = (wave & 1) * 64;    // wave tile origin in N
    const int quad = lane >> 4;          // 0..3
    const int m16  = lane & 15;

    const long bm0 = (long)blockIdx.y * BM;
    const long bn0 = (long)blockIdx.x * BN;

    // staging: chunk c in {0,1}: row = c*64 + tid/4, 16B slot = tid%4.
    // LDS byte offset = c*4096 + tid*16 (wave-uniform base + lane*16 rule OK).
    const int srow = tid >> 2;                 // 0..63
    const int scol = (tid & 3) * 8;            // element offset (8 bf16 = 16B)

    const unsigned short* gA = A + (bm0 + srow) * (long)K + scol;
    const unsigned short* gB = B + (bn0 + srow) * (long)K + scol;
    char* lA = (char*)sA + tid * 16;
    char* lB = (char*)sB + tid * 16;

    f32x4 acc[4][4];
    #pragma unroll
    for (int i = 0; i < 4; i++)
        #pragma unroll
        for (int j = 0; j < 4; j++)
            acc[i][j] = (f32x4)0.0f;

    for (int k0 = 0; k0 < K; k0 += BK) {
        load16_to_lds(gA + k0,                lA);
        load16_to_lds(gA + 64 * (long)K + k0, lA + 4096);
        load16_to_lds(gB + k0,                lB);
        load16_to_lds(gB + 64 * (long)K + k0, lB + 4096);
        __syncthreads();   // drains vmcnt before s_barrier

        bf16x8 af[4], bfr[4];
        #pragma unroll
        for (int i = 0; i < 4; i++)
            af[i]  = *(const bf16x8*)&sA[(wm + i * 16 + m16) * BK + quad * 8];
        #pragma unroll
        for (int j = 0; j < 4; j++)
            bfr[j] = *(const bf16x8*)&sB[(wn + j * 16 + m16) * BK + quad * 8];

        #pragma unroll
        for (int i = 0; i < 4; i++)
            #pragma unroll
            for (int j = 0; j < 4; j++)
                acc[i][j] = __builtin_amdgcn_mfma_f32_16x16x32_bf16(
                    af[i], bfr[j], acc[i][j], 0, 0, 0);

        __syncthreads();   // protect LDS before next staging
    }

    // epilogue: C/D layout col=lane&15, row=quad*4+reg (m89/m91)
    #pragma unroll
    for (int i = 0; i < 4; i++) {
        #pragma unroll
        for (int j = 0; j < 4; j++) {
            #pragma unroll
            for (int r = 0; r < 4; r++) {
                float v = acc[i][j][r];
                if (RELU2) v = (v > 0.0f) ? v * v : 0.0f;
                const long row = bm0 + wm + i * 16 + quad * 4 + r;
                const long col = bn0 + wn + j * 16 + m16;
                if (OUT_BF16)
                    ((unsigned short*)Cv)[row * (long)N + col] = f2bf(v);
                else
                    ((float*)Cv)[row * (long)N + col] = v;
            }
        }
    }
}

extern "C" void kernel_launch(void* const* d_in, const int* in_sizes, int n_in,
                              void* d_out, int out_size, void* d_ws, size_t ws_size,
                              hipStream_t stream) {
    (void)in_sizes; (void)n_in; (void)out_size; (void)ws_size;

    const int T = 8192, DIM = 1024, HID = 4096;

    const float* x     = (const float*)d_in[0];  // [T, DIM]    fp32
    const float* W_fc  = (const float*)d_in[1];  // [HID, DIM]  fp32
    const float* W_prj = (const float*)d_in[2];  // [DIM, HID]  fp32
    float* out = (float*)d_out;                  // [T, DIM]    fp32

    char* ws = (char*)d_ws;
    unsigned short* h   = (unsigned short*)ws;                          // 64 MiB [T,HID] bf16
    unsigned short* xb  = (unsigned short*)(ws + (64l << 20));          // 16 MiB [T,DIM]
    unsigned short* wfb = (unsigned short*)(ws + (80l << 20));          //  8 MiB [HID,DIM]
    unsigned short* wpb = (unsigned short*)(ws + (88l << 20));          //  8 MiB [DIM,HID]

    // --- prepass: fp32 -> bf16 -------------------------------------------
    const int nx = T * DIM / 4, nw1 = HID * DIM / 4, nw2 = DIM * HID / 4;
    cvt_f32_bf16<<<1024, 256, 0, stream>>>((const float4*)x,     (ushort4*)xb,  nx);
    cvt_f32_bf16<<<1024, 256, 0, stream>>>((const float4*)W_fc,  (ushort4*)wfb, nw1);
    cvt_f32_bf16<<<1024, 256, 0, stream>>>((const float4*)W_prj, (ushort4*)wpb, nw2);

    // --- GEMM1: h = relu(x . W_fc^T)^2  [8192,4096] bf16 ------------------
    gemm_bt<true, true><<<dim3(HID / BN, T / BM), dim3(256), 0, stream>>>(
        xb, wfb, h, T, HID, DIM);

    // --- GEMM2: out = h . W_proj^T      [8192,1024] fp32 ------------------
    gemm_bt<false, false><<<dim3(DIM / BN, T / BM), dim3(256), 0, stream>>>(
        h, wpb, out, T, DIM, HID);
}

// Round 3
// 276.321 us; speedup vs baseline: 1.0009x; 1.0009x over previous
//
#include <hip/hip_runtime.h>
#include <stdint.h>

// ============================================================================
// ExpertMLP: out = relu(x @ W_fc^T)^2 @ W_proj^T    (fp32 in/out, bf16 MFMA)
// R3: register-prefetch pipelined K-loop (global->VGPR->ds_write_b128),
//     XCD-aware block swizzle, fused fp32->bf16 prepass.
// ws: h[64Mi] | x_bf[16Mi] | wfc_bf[8Mi] | wproj_bf[8Mi] = 96 MiB.
// ============================================================================

#define BM 128
#define BN 128
#define BK 32

typedef __attribute__((ext_vector_type(8))) short bf16x8;   // 8 bf16 = 4 VGPRs
typedef __attribute__((ext_vector_type(4))) float f32x4;    // MFMA C/D

__device__ __forceinline__ unsigned short f2bf(float f) {
    unsigned int u = __float_as_uint(f);
    u += 0x7FFFu + ((u >> 16) & 1u);   // RNE; inputs are finite
    return (unsigned short)(u >> 16);
}

// --------------------------------------------------------------------------
// fused fp32 -> bf16 conversion for all three tensors, float4/ushort4
// --------------------------------------------------------------------------
__global__ void cvt3_f32_bf16(const float4* __restrict__ s0, ushort4* __restrict__ d0, int n0,
                              const float4* __restrict__ s1, ushort4* __restrict__ d1, int n1,
                              const float4* __restrict__ s2, ushort4* __restrict__ d2, int n2)
{
    int i = blockIdx.x * blockDim.x + threadIdx.x;
    const int stride = gridDim.x * blockDim.x;
    const int ntot = n0 + n1 + n2;
    for (; i < ntot; i += stride) {
        const float4* s; ushort4* d; int j = i;
        if (j < n0)             { s = s0; d = d0; }
        else if ((j -= n0) < n1){ s = s1; d = d1; }
        else                    { j -= n1; s = s2; d = d2; }
        float4 v = s[j];
        ushort4 o;
        o.x = f2bf(v.x); o.y = f2bf(v.y); o.z = f2bf(v.z); o.w = f2bf(v.w);
        d[j] = o;
    }
}

// --------------------------------------------------------------------------
// C[M,N] = A[M,K] . B[N,K]^T  (bf16-as-ushort inputs, fp32 accum)
// RELU2: relu(v)^2 epilogue. OUT_BF16: bf16 store else fp32.
// SWIZ 0: each XCD owns 8 M-strips, column-outer (A-span L2-resident).
// SWIZ 1: each XCD owns one N-column   (B-tile L2-resident).
// Pipelined: prefetch tile k+1 into VGPRs while computing tile k.
// --------------------------------------------------------------------------
template<bool RELU2, bool OUT_BF16, int SWIZ>
__global__ __launch_bounds__(256, 3)
void gemm_bt(const unsigned short* __restrict__ A,
             const unsigned short* __restrict__ B,
             void* __restrict__ Cv, int M, int N, int K)
{
    __shared__ unsigned short sA[BM * BK];   // 8 KiB, row-major [128][32]
    __shared__ unsigned short sB[BN * BK];   // 8 KiB

    const int tid  = threadIdx.x;
    const int lane = tid & 63;
    const int wave = tid >> 6;
    const int wm   = (wave >> 1) * 64;
    const int wn   = (wave & 1) * 64;
    const int quad = lane >> 4;
    const int m16  = lane & 15;

    // ---- XCD-aware swizzle (assumes lbid%8 round-robin XCD dispatch) -----
    const int lbid = blockIdx.y * gridDim.x + blockIdx.x;
    int bx, by;
    if (SWIZ == 1) {            // GEMM2: column per XCD
        bx = lbid & 7;
        by = lbid >> 3;
    } else {                    // GEMM1: 8 M-strips per XCD, column-outer
        const int xcd = lbid & 7;
        const int t   = lbid >> 3;
        by = xcd * 8 + (t & 7);
        bx = t >> 3;
    }

    const long bm0 = (long)by * BM;
    const long bn0 = (long)bx * BN;

    // staging: row = c*64 + tid/4, 16B slot = tid%4; LDS byte off = c*4096 + tid*16
    const int srow = tid >> 2;
    const int scol = (tid & 3) * 8;

    const unsigned short* pA = A + (bm0 + srow) * (long)K + scol;
    const unsigned short* pB = B + (bn0 + srow) * (long)K + scol;
    const long strideA = 64 * (long)K;
    char* lA = (char*)sA + tid * 16;
    char* lB = (char*)sB + tid * 16;

    f32x4 acc[4][4];
    #pragma unroll
    for (int i = 0; i < 4; i++)
        #pragma unroll
        for (int j = 0; j < 4; j++)
            acc[i][j] = (f32x4)0.0f;

    // ---- preload tile 0 into registers -----------------------------------
    uint4 ra0 = *(const uint4*)(pA);
    uint4 ra1 = *(const uint4*)(pA + strideA);
    uint4 rb0 = *(const uint4*)(pB);
    uint4 rb1 = *(const uint4*)(pB + strideA);

    for (int k0 = 0; k0 < K; k0 += BK) {
        // ---- commit current tile regs -> LDS (ds_write_b128 x4) ----------
        *(uint4*)lA          = ra0;
        *(uint4*)(lA + 4096) = ra1;
        *(uint4*)lB          = rb0;
        *(uint4*)(lB + 4096) = rb1;
        __syncthreads();

        // ---- issue prefetch of tile k+1 (waits land AFTER compute) -------
        if (k0 + BK < K) {
            pA += BK; pB += BK;
            ra0 = *(const uint4*)(pA);
            ra1 = *(const uint4*)(pA + strideA);
            rb0 = *(const uint4*)(pB);
            rb1 = *(const uint4*)(pB + strideA);
        }

        // ---- LDS -> fragments, 16 MFMAs ----------------------------------
        bf16x8 af[4], bfr[4];
        #pragma unroll
        for (int i = 0; i < 4; i++)
            af[i]  = *(const bf16x8*)&sA[(wm + i * 16 + m16) * BK + quad * 8];
        #pragma unroll
        for (int j = 0; j < 4; j++)
            bfr[j] = *(const bf16x8*)&sB[(wn + j * 16 + m16) * BK + quad * 8];

        #pragma unroll
        for (int i = 0; i < 4; i++)
            #pragma unroll
            for (int j = 0; j < 4; j++)
                acc[i][j] = __builtin_amdgcn_mfma_f32_16x16x32_bf16(
                    af[i], bfr[j], acc[i][j], 0, 0, 0);

        __syncthreads();   // LDS safe before next ds_write
    }

    // ---- epilogue: C/D layout col=lane&15, row=quad*4+reg ----------------
    #pragma unroll
    for (int i = 0; i < 4; i++) {
        #pragma unroll
        for (int j = 0; j < 4; j++) {
            #pragma unroll
            for (int r = 0; r < 4; r++) {
                float v = acc[i][j][r];
                if (RELU2) v = (v > 0.0f) ? v * v : 0.0f;
                const long row = bm0 + wm + i * 16 + quad * 4 + r;
                const long col = bn0 + wn + j * 16 + m16;
                if (OUT_BF16)
                    ((unsigned short*)Cv)[row * (long)N + col] = f2bf(v);
                else
                    ((float*)Cv)[row * (long)N + col] = v;
            }
        }
    }
}

extern "C" void kernel_launch(void* const* d_in, const int* in_sizes, int n_in,
                              void* d_out, int out_size, void* d_ws, size_t ws_size,
                              hipStream_t stream) {
    (void)in_sizes; (void)n_in; (void)out_size; (void)ws_size;

    const int T = 8192, DIM = 1024, HID = 4096;

    const float* x     = (const float*)d_in[0];  // [T, DIM]
    const float* W_fc  = (const float*)d_in[1];  // [HID, DIM]
    const float* W_prj = (const float*)d_in[2];  // [DIM, HID]
    float* out = (float*)d_out;                  // [T, DIM]

    char* ws = (char*)d_ws;
    unsigned short* h   = (unsigned short*)ws;                  // 64 MiB [T,HID]
    unsigned short* xb  = (unsigned short*)(ws + (64l << 20));  // 16 MiB
    unsigned short* wfb = (unsigned short*)(ws + (80l << 20));  //  8 MiB
    unsigned short* wpb = (unsigned short*)(ws + (88l << 20));  //  8 MiB

    // --- prepass: fp32 -> bf16 (one fused kernel) -------------------------
    cvt3_f32_bf16<<<2048, 256, 0, stream>>>(
        (const float4*)x,     (ushort4*)xb,  T * DIM / 4,
        (const float4*)W_fc,  (ushort4*)wfb, HID * DIM / 4,
        (const float4*)W_prj, (ushort4*)wpb, DIM * HID / 4);

    // --- GEMM1: h = relu(x . W_fc^T)^2  [8192,4096] bf16 ------------------
    gemm_bt<true, true, 0><<<dim3(HID / BN, T / BM), dim3(256), 0, stream>>>(
        xb, wfb, h, T, HID, DIM);

    // --- GEMM2: out = h . W_proj^T      [8192,1024] fp32 ------------------
    gemm_bt<false, false, 1><<<dim3(DIM / BN, T / BM), dim3(256), 0, stream>>>(
        h, wpb, out, T, DIM, HID);
}